// Round 7
// baseline (99.928 us; speedup 1.0000x reference)
//
#include <hip/hip_runtime.h>
#include <hip/hip_bf16.h>

typedef float f32x4 __attribute__((ext_vector_type(4)));
typedef short s16x8 __attribute__((ext_vector_type(8)));

#define D_DIM 4096
#define NT 24            // 16-wide col tiles
#define NSLAB_H 64       // K slabs of 32 per K-half
#define BM 64            // rows per block
#define DSTRIDE 392      // Dmat row stride (floats), 16B-aligned rows
#define POOL_BYTES (64 * DSTRIDE * 4)   // 100352; A-bufs (16KB) alias the front
// ws byte offsets
#define PART_OFF (4u << 20)              // part[2][128][64*384] f32 = 24 MiB
#define SINW_OFF (28u << 20)             // sinws[4][8192] f32 = 128 KiB

__device__ __forceinline__ unsigned short f2bf(float f) {
    unsigned u = __float_as_uint(f);
    u += 0x7fffu + ((u >> 16) & 1u);   // RNE
    return (unsigned short)(u >> 16);
}

__global__ __launch_bounds__(64) void reg_init_kernel(const float* __restrict__ C,
                                                      const float* __restrict__ Csin,
                                                      float* __restrict__ reg_out) {
    if (threadIdx.x == 0)
        reg_out[0] = 0.05f * (fabsf(C[0]) + fabsf(C[1]) + fabsf(C[2]) + fabsf(Csin[0]));
}

// Build W [4096 x 384] bf16, MFMA B-fragment-packed, slab-contiguous:
// chunk = (k>>5)*NT + (n>>4); lane = ((k&31)>>3)*16 | (n&15); j = k&7.
__global__ __launch_bounds__(64) void build_w_kernel(const float* __restrict__ U1,
                                                     const float* __restrict__ U2,
                                                     const float* __restrict__ U3,
                                                     unsigned short* __restrict__ W,
                                                     float* __restrict__ reg_out) {
    const int ks = blockIdx.x / NT;
    const int ct = blockIdx.x % NT;
    const int l  = threadIdx.x;
    const int n  = ct * 16 + (l & 15);
    const int kb = ks * 32 + ((l >> 4) << 3);

    const float* src;
    float scale;
    if (n < 64)       { src = U1 + n;                  scale = 0.01f / 262144.f; }
    else if (n < 128) { src = U2 + (n - 64);           scale = 0.01f / 524288.f; }
    else if (n < 192) { src = U2 + 262144 + (n - 128); scale = 0.01f / 524288.f; }
    else if (n < 256) { src = U3 + (n - 192);          scale = 0.01f / 786432.f; }
    else if (n < 320) { src = U3 + 262144 + (n - 256); scale = 0.01f / 786432.f; }
    else              { src = U3 + 524288 + (n - 320); scale = 0.01f / 786432.f; }

    unsigned short h[8];
    float sabs = 0.f;
#pragma unroll
    for (int j = 0; j < 8; ++j) {
        float u = src[(size_t)(kb + j) * 64];
        sabs += fabsf(u);
        h[j] = f2bf(u);
    }
    uint4 pk;
    pk.x = (unsigned)h[0] | ((unsigned)h[1] << 16);
    pk.y = (unsigned)h[2] | ((unsigned)h[3] << 16);
    pk.z = (unsigned)h[4] | ((unsigned)h[5] << 16);
    pk.w = (unsigned)h[6] | ((unsigned)h[7] << 16);
    *(uint4*)(W + ((size_t)blockIdx.x * 64 + l) * 8) = pk;

    sabs *= scale;
#pragma unroll
    for (int off = 32; off >= 1; off >>= 1)
        sabs += __shfl_xor(sabs, off, 64);
    if (l == 0) atomicAdd(reg_out, sabs);
}

// grid 256 = (rb 0..127) x (kh 0..1). Block: 64 rows x 384 cols x 2048 k.
// 16 waves = 2 kg (k-parity) x 8 cg (3 col-tiles). Wave: 4 row-frags x 3 B-frags
// = 12 MFMA/body. B frags from L2-resident frag-packed W, 2-deep reg rotation;
// X 3-deep; A slab (64x32 bf16, 4KB) LDS-staged by all 1024 threads, 4 buffers.
// Raw s_barrier + lgkmcnt-only drain; 32 barrier intervals total.
__global__ __launch_bounds__(1024) void poly_main_kernel(const float* __restrict__ X,
                                                         const unsigned short* __restrict__ W,
                                                         float* __restrict__ part,
                                                         float* __restrict__ sinws) {
    __shared__ __align__(16) char pool[POOL_BYTES];

    const int t    = threadIdx.x;
    const int lane = t & 63;
    const int wv   = t >> 6;
    const int kg   = wv >> 3;
    const int cg   = wv & 7;
    const int ct0  = cg * 3;
    const int rb   = blockIdx.x >> 1;
    const int kh   = blockIdx.x & 1;
    const int row0 = rb * BM;

    const int p    = t >> 9;              // stage parity
    const int srow = (t >> 3) & 63;
    const int k4   = (t & 7) << 2;
    const float* xp = X + (size_t)(row0 + srow) * D_DIM + kh * 2048 + k4;
    const int awfrag = (srow >> 4) * 1024
                     + (((((k4 >> 3) & 3) << 4) | (srow & 15)) * 16) + ((k4 & 7) << 1);

    const s16x8* __restrict__ Wh = (const s16x8*)W + (size_t)kh * NSLAB_H * NT * 64;

    f32x4 acc[4][3];
#pragma unroll
    for (int r = 0; r < 4; ++r)
#pragma unroll
        for (int c = 0; c < 3; ++c) acc[r][c] = (f32x4){0.f, 0.f, 0.f, 0.f};
    float sinacc = 0.f;
    f32x4 xw{}, xa{}, xb{};

    // ---- prologue ----
    {
        f32x4 x0 = *(const f32x4*)(xp + (size_t)p * 32);
        sinacc += __sinf(x0.x) + __sinf(x0.y) + __sinf(x0.z) + __sinf(x0.w);
        short4 h;
        h.x = (short)f2bf(x0.x); h.y = (short)f2bf(x0.y);
        h.z = (short)f2bf(x0.z); h.w = (short)f2bf(x0.w);
        *(short4*)(pool + p * 4096 + awfrag) = h;
        xw = *(const f32x4*)(xp + (size_t)(2 + p) * 32);   // staged @ d=0
        xa = *(const f32x4*)(xp + (size_t)(4 + p) * 32);   // staged @ d=1
        xb = *(const f32x4*)(xp + (size_t)(6 + p) * 32);   // staged @ d=2
    }
    s16x8 bA0 = Wh[((size_t)kg * NT + ct0 + 0) * 64 + lane];
    s16x8 bA1 = Wh[((size_t)kg * NT + ct0 + 1) * 64 + lane];
    s16x8 bA2 = Wh[((size_t)kg * NT + ct0 + 2) * 64 + lane];
    s16x8 bB0{}, bB1{}, bB2{};
    asm volatile("s_waitcnt lgkmcnt(0)" ::: "memory");
    __builtin_amdgcn_s_barrier();
    __builtin_amdgcn_sched_barrier(0);

#define BODY(d_, U0, U1, U2, P0, P1, P2, XW)                                    \
    {                                                                           \
        const int d__ = (d_);                                                   \
        const int sw_ = 2 * d__ + 2 + p;                                        \
        if (sw_ < NSLAB_H) {                                                    \
            sinacc += __sinf(XW.x) + __sinf(XW.y)                               \
                    + __sinf(XW.z) + __sinf(XW.w);                              \
            short4 h_;                                                          \
            h_.x = (short)f2bf(XW.x); h_.y = (short)f2bf(XW.y);                 \
            h_.z = (short)f2bf(XW.z); h_.w = (short)f2bf(XW.w);                 \
            *(short4*)(pool + (sw_ & 3) * 4096 + awfrag) = h_;                  \
        }                                                                       \
        int sl_ = 2 * d__ + 8 + p; if (sl_ > NSLAB_H - 1) sl_ = NSLAB_H - 1;    \
        XW = *(const f32x4*)(xp + (size_t)sl_ * 32);                            \
        int sp_ = 2 * d__ + 2 + kg; if (sp_ > NSLAB_H - 1) sp_ = NSLAB_H - 1;   \
        P0 = Wh[((size_t)sp_ * NT + ct0 + 0) * 64 + lane];                      \
        P1 = Wh[((size_t)sp_ * NT + ct0 + 1) * 64 + lane];                      \
        P2 = Wh[((size_t)sp_ * NT + ct0 + 2) * 64 + lane];                      \
        const int ab_ = ((2 * d__ + kg) & 3) * 4096;                            \
        s16x8 af0_ = *(const s16x8*)(pool + ab_ + 0 * 1024 + lane * 16);        \
        s16x8 af1_ = *(const s16x8*)(pool + ab_ + 1 * 1024 + lane * 16);        \
        s16x8 af2_ = *(const s16x8*)(pool + ab_ + 2 * 1024 + lane * 16);        \
        s16x8 af3_ = *(const s16x8*)(pool + ab_ + 3 * 1024 + lane * 16);        \
        asm volatile("s_waitcnt lgkmcnt(0)" ::: "memory");                      \
        __builtin_amdgcn_sched_barrier(0);                                      \
        __builtin_amdgcn_s_setprio(1);                                          \
        acc[0][0] = __builtin_amdgcn_mfma_f32_16x16x32_bf16(af0_, U0, acc[0][0], 0, 0, 0); \
        acc[0][1] = __builtin_amdgcn_mfma_f32_16x16x32_bf16(af0_, U1, acc[0][1], 0, 0, 0); \
        acc[0][2] = __builtin_amdgcn_mfma_f32_16x16x32_bf16(af0_, U2, acc[0][2], 0, 0, 0); \
        acc[1][0] = __builtin_amdgcn_mfma_f32_16x16x32_bf16(af1_, U0, acc[1][0], 0, 0, 0); \
        acc[1][1] = __builtin_amdgcn_mfma_f32_16x16x32_bf16(af1_, U1, acc[1][1], 0, 0, 0); \
        acc[1][2] = __builtin_amdgcn_mfma_f32_16x16x32_bf16(af1_, U2, acc[1][2], 0, 0, 0); \
        acc[2][0] = __builtin_amdgcn_mfma_f32_16x16x32_bf16(af2_, U0, acc[2][0], 0, 0, 0); \
        acc[2][1] = __builtin_amdgcn_mfma_f32_16x16x32_bf16(af2_, U1, acc[2][1], 0, 0, 0); \
        acc[2][2] = __builtin_amdgcn_mfma_f32_16x16x32_bf16(af2_, U2, acc[2][2], 0, 0, 0); \
        acc[3][0] = __builtin_amdgcn_mfma_f32_16x16x32_bf16(af3_, U0, acc[3][0], 0, 0, 0); \
        acc[3][1] = __builtin_amdgcn_mfma_f32_16x16x32_bf16(af3_, U1, acc[3][1], 0, 0, 0); \
        acc[3][2] = __builtin_amdgcn_mfma_f32_16x16x32_bf16(af3_, U2, acc[3][2], 0, 0, 0); \
        __builtin_amdgcn_s_setprio(0);                                          \
        __builtin_amdgcn_s_barrier();                                           \
        __builtin_amdgcn_sched_barrier(0);                                      \
    }

    // 6-body unroll aligns the 2-set B rotation with the 3-reg X rotation.
    for (int e = 0; e < 5; ++e) {
        const int d0 = 6 * e;
        BODY(d0 + 0, bA0, bA1, bA2, bB0, bB1, bB2, xw);
        BODY(d0 + 1, bB0, bB1, bB2, bA0, bA1, bA2, xa);
        BODY(d0 + 2, bA0, bA1, bA2, bB0, bB1, bB2, xb);
        BODY(d0 + 3, bB0, bB1, bB2, bA0, bA1, bA2, xw);
        BODY(d0 + 4, bA0, bA1, bA2, bB0, bB1, bB2, xa);
        BODY(d0 + 5, bB0, bB1, bB2, bA0, bA1, bA2, xb);
    }
    BODY(30, bA0, bA1, bA2, bB0, bB1, bB2, xw);
    BODY(31, bB0, bB1, bB2, bA0, bA1, bA2, xa);
#undef BODY

    // ---- epilogue: merge kg partials in LDS, write part + sin ----
    float* Dm = (float*)pool;
    const int lr4 = (lane >> 4) << 2;
    const int lc  = lane & 15;

    if (kg == 0) {
#pragma unroll
        for (int r = 0; r < 4; ++r)
#pragma unroll
            for (int c = 0; c < 3; ++c) {
                const int col = (ct0 + c) * 16 + lc;
#pragma unroll
                for (int i = 0; i < 4; ++i)
                    Dm[(r * 16 + lr4 + i) * DSTRIDE + col] = acc[r][c][i];
            }
    }
    __syncthreads();
    if (kg == 1) {
#pragma unroll
        for (int r = 0; r < 4; ++r)
#pragma unroll
            for (int c = 0; c < 3; ++c) {
                const int col = (ct0 + c) * 16 + lc;
#pragma unroll
                for (int i = 0; i < 4; ++i)
                    Dm[(r * 16 + lr4 + i) * DSTRIDE + col] += acc[r][c][i];
            }
    }
    sinacc += __shfl_xor(sinacc, 1);
    sinacc += __shfl_xor(sinacc, 2);
    sinacc += __shfl_xor(sinacc, 4);
    if ((t & 7) == 0)
        sinws[(size_t)(kh * 2 + p) * 8192 + row0 + srow] = sinacc;
    __syncthreads();

    float* pb = part + ((size_t)kh * 128 + rb) * (BM * 384);
    const int prow = t >> 4;
    const int pc0  = (t & 15) * 24;
#pragma unroll
    for (int v = 0; v < 6; ++v)
        *(f32x4*)(pb + (size_t)prow * 384 + pc0 + v * 4) =
            *(const f32x4*)(Dm + prow * DSTRIDE + pc0 + v * 4);
}

__global__ __launch_bounds__(512) void combine_kernel(const float* __restrict__ part,
                                                      const float* __restrict__ sinws,
                                                      const float* __restrict__ C,
                                                      const float* __restrict__ beta,
                                                      const float* __restrict__ Csin,
                                                      float* __restrict__ out) {
    const int t   = threadIdx.x;
    const int row = blockIdx.x * 32 + (t >> 4);
    const int cc  = t & 15;
    const int rb  = row >> 6;
    const int lr  = row & 63;
    const float* p0 = part + (size_t)rb * (64 * 384) + (size_t)lr * 384;
    const float* p1 = p0 + (size_t)128 * (64 * 384);

    float t1 = 0.f, t2 = 0.f, t3 = 0.f;
#pragma unroll
    for (int rr = 0; rr < 64; rr += 16) {
        const int c = rr + cc;
        const float d1 = p0[c]       + p1[c];
        const float a2 = p0[64 + c]  + p1[64 + c];
        const float b2 = p0[128 + c] + p1[128 + c];
        const float a3 = p0[192 + c] + p1[192 + c];
        const float b3 = p0[256 + c] + p1[256 + c];
        const float c3 = p0[320 + c] + p1[320 + c];
        t1 += d1;
        t2 += a2 * b2;
        t3 += a3 * b3 * c3;
    }
#pragma unroll
    for (int off = 1; off < 16; off <<= 1) {
        t1 += __shfl_xor(t1, off, 16);
        t2 += __shfl_xor(t2, off, 16);
        t3 += __shfl_xor(t3, off, 16);
    }
    if (cc == 0) {
        const float s = sinws[row] + sinws[8192 + row]
                      + sinws[2 * 8192 + row] + sinws[3 * 8192 + row];
        out[row] = beta[0] + C[0] * t1 + C[1] * t2 + C[2] * t3 + Csin[0] * s;
    }
}

extern "C" void kernel_launch(void* const* d_in, const int* in_sizes, int n_in,
                              void* d_out, int out_size, void* d_ws, size_t ws_size,
                              hipStream_t stream) {
    const float* X   = (const float*)d_in[0];
    const float* U1  = (const float*)d_in[1];
    const float* U2  = (const float*)d_in[2];
    const float* U3  = (const float*)d_in[3];
    const float* Cc  = (const float*)d_in[4];
    const float* bet = (const float*)d_in[5];
    const float* Cs  = (const float*)d_in[6];
    float* out = (float*)d_out;

    unsigned short* W = (unsigned short*)d_ws;                 // 3 MiB, frag-packed
    float* part  = (float*)((char*)d_ws + PART_OFF);           // 24 MiB
    float* sinws = (float*)((char*)d_ws + SINW_OFF);           // 128 KiB

    reg_init_kernel<<<1, 64, 0, stream>>>(Cc, Cs, out + 8192);
    build_w_kernel<<<128 * NT, 64, 0, stream>>>(U1, U2, U3, W, out + 8192);
    poly_main_kernel<<<256, 1024, 0, stream>>>(X, W, part, sinws);
    combine_kernel<<<256, 512, 0, stream>>>(part, sinws, Cc, bet, Cs, out);
}